// Round 3
// baseline (680.714 us; speedup 1.0000x reference)
//
#include <hip/hip_runtime.h>
#include <hip/hip_bf16.h>
#include <math.h>

// MultiBoxLoss fused: B=64, P=16800, G=32, C=2.
// One block per batch does IoU+match+losses+exact top-k entirely in
// registers/LDS (no global atomics, no workspace round-trips).
// k_final (1 wave) reduces the 64 per-batch partials.

#define RCP(x) __builtin_amdgcn_rcpf(x)

constexpr int NT = 1024;       // threads per block (16 waves)
constexpr int NW = NT / 64;
constexpr int GN = 32;         // ground truths per batch
constexpr int NITER = 17;      // ceil(16800 / 1024)

__device__ __forceinline__ float sl1(float x) {
    float a = fabsf(x);
    return a < 1.f ? 0.5f * a * a : a - 0.5f;
}

__global__ __launch_bounds__(NT)
void k_main(const float2* __restrict__ cls, const float4* __restrict__ loc,
            const float* __restrict__ lmd, const float4* __restrict__ priors,
            const float* __restrict__ targets, float* __restrict__ part, int P) {
    const int b = blockIdx.x, tid = threadIdx.x;
    const int lane = tid & 63, w = tid >> 6;

    __shared__ float4 s_box[GN];                 // gt boxes (corner form)
    __shared__ float  s_at[GN];                  // gt areas
    __shared__ float  s_lm[GN * 10];             // gt landmarks
    __shared__ float  s_lab[GN];                 // labels (+-1)
    __shared__ unsigned long long s_wk[NW][GN];  // per-wave reduced gt keys
    __shared__ unsigned s_kl[GN];                // low32 of final key = ~best_p
    __shared__ unsigned char s_pb[NITER * NT];   // per-prior: (btv>=0.35)<<5 | bti
    __shared__ float s_red[NW];
    __shared__ int   s_redi[NW];
    __shared__ unsigned s_vmb;
    __shared__ float s_f0;
    __shared__ int   s_i0;

    // ---- stage targets ----
    if (tid < GN * 15) {
        int g = tid / 15, j = tid % 15;
        float v = targets[((size_t)b * GN + g) * 15 + j];
        if (j < 4) ((float*)&s_box[g])[j] = v;
        else if (j < 14) s_lm[g * 10 + (j - 4)] = v;
        else s_lab[g] = v;
    }
    __syncthreads();
    if (tid < GN) { float4 t = s_box[tid]; s_at[tid] = (t.z - t.x) * (t.w - t.y); }
    __syncthreads();

    // ---- phase 1: IoU; per-thread running per-gt best key; per-prior best ----
    unsigned long long kk[GN];
    #pragma unroll
    for (int g = 0; g < GN; ++g) kk[g] = 0ull;

    for (int i = 0; i < NITER; ++i) {
        int p = i * NT + tid;
        bool act = p < P;
        float4 pr = act ? priors[p] : make_float4(1e9f, 1e9f, 1.f, 1.f);
        float hx = pr.z * 0.5f, hy = pr.w * 0.5f;
        float px0 = pr.x - hx, py0 = pr.y - hy;
        float px1 = pr.x + hx, py1 = pr.y + hy;
        float ap = (px1 - px0) * (py1 - py0);
        float btv = -1.f; int bti = 0;
        unsigned npk = ~(unsigned)p;
        #pragma unroll
        for (int g = 0; g < GN; ++g) {
            float4 tb = s_box[g];
            float lx = fmaxf(tb.x, px0), ly = fmaxf(tb.y, py0);
            float rx = fminf(tb.z, px1), ry = fminf(tb.w, py1);
            float iw = fmaxf(rx - lx, 0.f), ih = fmaxf(ry - ly, 0.f);
            float inter = iw * ih;
            float iou = inter * RCP(s_at[g] + ap - inter);
            if (iou > btv) { btv = iou; bti = g; }   // first-index max over g
            unsigned long long key =
                ((unsigned long long)__float_as_uint(iou) << 32) | npk;
            if (act && key > kk[g]) kk[g] = key;     // max iou, then smallest p
        }
        if (act) s_pb[p] = (unsigned char)((btv >= 0.35f ? 32 : 0) | bti);
    }

    // ---- phase 1b: reduce per-gt keys: wave shuffle -> LDS -> 32 threads ----
    #pragma unroll
    for (int g = 0; g < GN; ++g) {
        unsigned long long k2 = kk[g];
        #pragma unroll
        for (int o = 32; o > 0; o >>= 1) {
            unsigned long long t = __shfl_down(k2, o, 64);
            if (t > k2) k2 = t;
        }
        if (lane == 0) s_wk[w][g] = k2;
    }
    __syncthreads();
    if (tid < GN) {
        unsigned long long m = 0ull;
        #pragma unroll
        for (int q = 0; q < NW; ++q) { unsigned long long t = s_wk[q][tid]; if (t > m) m = t; }
        s_kl[tid] = (unsigned)m;                       // = ~best_prior_idx
        float bpov = __uint_as_float((unsigned)(m >> 32));
        unsigned long long bal = __ballot(bpov >= 0.2f);   // valid_gt mask (lanes 0..31)
        if (tid == 0) s_vmb = (unsigned)bal;
    }
    __syncthreads();
    const unsigned vm = s_vmb;
    const bool av = vm != 0;

    // ---- phase 2: conf + losses; keep conf-loss bits in registers ----
    unsigned kl[GN];
    #pragma unroll
    for (int g = 0; g < GN; ++g) kl[g] = s_kl[g];

    unsigned ul[NITER];
    float a_ll = 0.f, a_lm = 0.f, a_lcp = 0.f;
    int a_np = 0, a_np1 = 0;
    #pragma unroll
    for (int i = 0; i < NITER; ++i) {
        int p = i * NT + tid;
        unsigned u = 0u;
        if (p < P) {
            unsigned pb = s_pb[p];
            unsigned npk = ~(unsigned)p;
            int fidx = -1; bool fv = false;
            #pragma unroll
            for (int g = 0; g < GN; ++g)
                if (kl[g] == npk) { fidx = g; fv = fv || ((vm >> g) & 1u); }
            bool thr = (pb & 32u) != 0u;
            int bti2 = fidx >= 0 ? fidx : (int)(pb & 31u);
            bool pos = av && (fv || thr);            // conf != 0
            float lab = s_lab[bti2];
            bool posl = pos && lab > 0.f;            // conf > 0

            float2 c = cls[(size_t)b * P + p];
            float d = c.y - c.x;
            float m0 = fmaxf(d, 0.f);
            float lse = m0 + __logf(__expf(-m0) + __expf(d - m0)); // logz - c.x >= 0
            u = pos ? 0u : __float_as_uint(lse);
            if (pos) {
                a_np++;
                a_lcp += lse - d;                    // logz - c.y
                float4 pr = priors[p];
                float4 tb = s_box[bti2];
                float rw = RCP(pr.z) * 10.f, rh = RCP(pr.w) * 10.f;
                float e0 = ((tb.x + tb.z) * 0.5f - pr.x) * rw;
                float e1 = ((tb.y + tb.w) * 0.5f - pr.y) * rh;
                float e2 = __logf((tb.z - tb.x) * RCP(pr.z)) * 5.f;
                float e3 = __logf((tb.w - tb.y) * RCP(pr.w)) * 5.f;
                float4 ld = loc[(size_t)b * P + p];
                a_ll += sl1(ld.x - e0) + sl1(ld.y - e1) + sl1(ld.z - e2) + sl1(ld.w - e3);
                if (posl) {
                    a_np1++;
                    const float* lp = lmd + ((size_t)b * P + p) * 10;
                    #pragma unroll
                    for (int q = 0; q < 5; ++q) {
                        float gx = (s_lm[bti2 * 10 + 2 * q]     - pr.x) * rw;
                        float gy = (s_lm[bti2 * 10 + 2 * q + 1] - pr.y) * rh;
                        a_lm += sl1(lp[2 * q] - gx) + sl1(lp[2 * q + 1] - gy);
                    }
                }
            }
        }
        ul[i] = u;
    }

    // ---- block-sum helper (2 barriers; safe for back-to-back calls) ----
    auto bsum = [&](float v) -> float {
        #pragma unroll
        for (int o = 32; o > 0; o >>= 1) v += __shfl_down(v, o, 64);
        if (lane == 0) s_red[w] = v;
        __syncthreads();
        if (tid == 0) {
            float r = 0.f;
            #pragma unroll
            for (int q = 0; q < NW; ++q) r += s_red[q];
            s_f0 = r;
        }
        __syncthreads();
        return s_f0;
    };

    float t_ll  = bsum(a_ll);
    float t_lm  = bsum(a_lm);
    float t_lcp = bsum(a_lcp);
    float t_np  = bsum((float)a_np);
    float t_np1 = bsum((float)a_np1);
    int np = (int)(t_np + 0.5f);

    // ---- phase 4: exact k-th largest via bisection on float bits ----
    int k = np * 7;
    if (k > P - 1) k = P - 1;
    float topk = 0.f;
    if (k > 0) {
        unsigned lo = 0u, hi = 0x7f800000u;   // values finite, >= 0
        while (lo < hi) {
            unsigned mid = lo + ((hi - lo + 1) >> 1);
            int cnt = 0;
            #pragma unroll
            for (int i = 0; i < NITER; ++i) cnt += (ul[i] >= mid) ? 1 : 0;
            #pragma unroll
            for (int o = 32; o > 0; o >>= 1) cnt += __shfl_down(cnt, o, 64);
            if (lane == 0) s_redi[w] = cnt;
            __syncthreads();
            if (tid == 0) {
                int r = 0;
                #pragma unroll
                for (int q = 0; q < NW; ++q) r += s_redi[q];
                s_i0 = r;
            }
            __syncthreads();
            int dcnt = s_i0;
            if (dcnt >= k) lo = mid; else hi = mid - 1;
        }
        unsigned T = lo;                       // k-th largest value (bit-exact)
        float fT = __uint_as_float(T);
        float s = 0.f; int c = 0;
        #pragma unroll
        for (int i = 0; i < NITER; ++i) {
            if (ul[i] > T) { s += __uint_as_float(ul[i]); c++; }
        }
        float ts = bsum(s);
        float tc = bsum((float)c);
        topk = ts + ((float)k - tc) * fT;      // ties at T contribute (k-cnt)*T
    }

    if (tid == 0) {
        float* pp = part + b * 8;
        pp[0] = t_ll; pp[1] = t_lm; pp[2] = t_lcp;
        pp[3] = topk; pp[4] = t_np; pp[5] = t_np1;
    }
}

__global__ void k_final(const float* __restrict__ part, float* __restrict__ out, int B) {
    int lane = threadIdx.x;
    float ll = 0, lm = 0, lcp = 0, tk = 0, np = 0, np1 = 0;
    for (int b = lane; b < B; b += 64) {
        const float* pp = part + b * 8;
        ll += pp[0]; lm += pp[1]; lcp += pp[2];
        tk += pp[3]; np += pp[4]; np1 += pp[5];
    }
    #pragma unroll
    for (int o = 32; o > 0; o >>= 1) {
        ll  += __shfl_down(ll, o, 64);
        lm  += __shfl_down(lm, o, 64);
        lcp += __shfl_down(lcp, o, 64);
        tk  += __shfl_down(tk, o, 64);
        np  += __shfl_down(np, o, 64);
        np1 += __shfl_down(np1, o, 64);
    }
    if (lane == 0) {
        float N = fmaxf(np, 1.f), N1 = fmaxf(np1, 1.f);
        out[0] = ll / N;
        out[1] = (lcp + tk) / N;
        out[2] = lm / N1;
    }
}

extern "C" void kernel_launch(void* const* d_in, const int* in_sizes, int n_in,
                              void* d_out, int out_size, void* d_ws, size_t ws_size,
                              hipStream_t stream) {
    const float2* cls    = (const float2*)d_in[0];
    const float4* loc    = (const float4*)d_in[1];
    const float* lmd     = (const float*)d_in[2];
    const float4* priors = (const float4*)d_in[3];
    const float* targets = (const float*)d_in[4];
    int P = in_sizes[3] / 4;          // 16800
    int B = (in_sizes[1] / 4) / P;    // 64

    float* part = (float*)d_ws;       // B * 8 floats, fully rewritten each call

    k_main<<<B, NT, 0, stream>>>(cls, loc, lmd, priors, targets, part, P);
    k_final<<<1, 64, 0, stream>>>(part, (float*)d_out, B);
}

// Round 4
// 138.095 us; speedup vs baseline: 4.9293x; 4.9293x over previous
//
#include <hip/hip_runtime.h>
#include <hip/hip_bf16.h>
#include <math.h>

// MultiBoxLoss: B=64, P=16800, G=32, C=2. Fully atomic-free pipeline:
// k_prior  (NBxB blocks): IoU once; per-prior best-truth -> btv/bti;
//                         per-gt best-prior keys block-reduced -> wkeys.
// k_keys   (B blocks):    reduce wkeys over blocks -> final keys + valid mask.
// k_match  (NBxB blocks): forced-match + conf + losses; per-block partials.
// k_select (B blocks):    reduce partials; exact k-th largest via bisection
//                         on register-resident conf-losses; per-batch row.
// k_final  (1 wave):      reduce 64 rows -> 3 scalars.

#define RCP(x) __builtin_amdgcn_rcpf(x)

constexpr int GN = 32;

__device__ __forceinline__ float sl1(float x) {
    float a = fabsf(x);
    return a < 1.f ? 0.5f * a * a : a - 0.5f;
}

// ---- k_prior ----
template<bool STORE>
__global__ __launch_bounds__(256)
void k_prior(const float4* __restrict__ priors, const float* __restrict__ targets,
             unsigned long long* __restrict__ wkeys, float* __restrict__ btv,
             unsigned char* __restrict__ bti, int P, int NB) {
    const int b = blockIdx.y, bx = blockIdx.x, tid = threadIdx.x;
    const int lane = tid & 63, w = tid >> 6;
    __shared__ float4 s_box[GN];
    __shared__ float  s_at[GN];
    __shared__ unsigned long long s_wk[4][GN];
    if (tid < GN) {
        const float* t = targets + ((size_t)b * GN + tid) * 15;
        float4 v = make_float4(t[0], t[1], t[2], t[3]);
        s_box[tid] = v;
        s_at[tid] = (v.z - v.x) * (v.w - v.y);
    }
    __syncthreads();
    int p = bx * 256 + tid;
    bool act = p < P;
    float4 pr = act ? priors[p] : make_float4(1e9f, 1e9f, 1.f, 1.f);
    float hx = pr.z * 0.5f, hy = pr.w * 0.5f;
    float px0 = pr.x - hx, py0 = pr.y - hy;
    float px1 = pr.x + hx, py1 = pr.y + hy;
    float ap = (px1 - px0) * (py1 - py0);
    float btv_r = -1.f; int bti_r = 0;
    unsigned npk = ~(unsigned)p;
    #pragma unroll
    for (int g = 0; g < GN; ++g) {
        float4 tb = s_box[g];
        float lx = fmaxf(tb.x, px0), ly = fmaxf(tb.y, py0);
        float rx = fminf(tb.z, px1), ry = fminf(tb.w, py1);
        float iw = fmaxf(rx - lx, 0.f), ih = fmaxf(ry - ly, 0.f);
        float inter = iw * ih;
        float iou = inter * RCP(s_at[g] + ap - inter);
        if (iou > btv_r) { btv_r = iou; bti_r = g; }   // first-index argmax over g
        unsigned long long key =
            act ? (((unsigned long long)__float_as_uint(iou) << 32) | npk) : 0ull;
        #pragma unroll
        for (int o = 32; o > 0; o >>= 1) {
            unsigned long long t = __shfl_down(key, o, 64);
            if (t > key) key = t;
        }
        if (lane == 0) s_wk[w][g] = key;               // max iou, then smallest p
    }
    __syncthreads();
    if (STORE && act) {
        btv[(size_t)b * P + p] = btv_r;
        bti[(size_t)b * P + p] = (unsigned char)bti_r;
    }
    if (tid < GN) {
        unsigned long long m = 0ull;
        #pragma unroll
        for (int q = 0; q < 4; ++q) { unsigned long long t = s_wk[q][tid]; if (t > m) m = t; }
        wkeys[((size_t)b * NB + bx) * GN + tid] = m;
    }
}

// ---- k_keys: finalize per-gt winners + valid mask ----
__global__ __launch_bounds__(256)
void k_keys(const unsigned long long* __restrict__ wkeys,
            unsigned long long* __restrict__ keys, unsigned* __restrict__ vmask, int NB) {
    const int b = blockIdx.x, tid = threadIdx.x;
    const int g = tid & 31, c = tid >> 5;              // 8 chunks x 32 gts
    __shared__ unsigned long long s_pk[8][GN];
    unsigned long long m = 0ull;
    for (int bx = c; bx < NB; bx += 8) {
        unsigned long long t = wkeys[((size_t)b * NB + bx) * GN + g];
        if (t > m) m = t;
    }
    s_pk[c][g] = m;
    __syncthreads();
    unsigned long long fm = 0ull;
    if (tid < GN) {
        #pragma unroll
        for (int q = 0; q < 8; ++q) { unsigned long long t = s_pk[q][tid]; if (t > fm) fm = t; }
        keys[b * GN + tid] = fm;
    }
    unsigned long long bal =
        __ballot(tid < GN && __uint_as_float((unsigned)(fm >> 32)) >= 0.2f);
    if (tid == 0) vmask[b] = (unsigned)bal;
}

// ---- k_match: per-prior conf + losses; per-block partials (no atomics) ----
template<bool STORED>
__global__ __launch_bounds__(256)
void k_match(const float2* __restrict__ cls, const float4* __restrict__ loc,
             const float* __restrict__ lmd, const float4* __restrict__ priors,
             const float* __restrict__ targets,
             const unsigned long long* __restrict__ keys, const unsigned* __restrict__ vmask,
             const float* __restrict__ btvA, const unsigned char* __restrict__ btiA,
             float* __restrict__ bc, float* __restrict__ part, int P, int NB) {
    const int b = blockIdx.y, bx = blockIdx.x, tid = threadIdx.x;
    const int lane = tid & 63, w = tid >> 6;
    __shared__ float s_t[GN * 4];
    __shared__ float s_at[GN];
    __shared__ float s_lm[GN * 10];
    __shared__ float s_lab[GN];
    __shared__ unsigned s_kl[GN];
    __shared__ float s_red[4][8];
    for (int i = tid; i < GN * 15; i += 256) {
        int g = i / 15, j = i - g * 15;
        float v = targets[((size_t)b * GN + g) * 15 + j];
        if (j < 4) s_t[g * 4 + j] = v;
        else if (j < 14) s_lm[g * 10 + (j - 4)] = v;
        else s_lab[g] = v;
    }
    if (tid < GN) s_kl[tid] = (unsigned)keys[b * GN + tid];
    __syncthreads();
    if (!STORED && tid < GN)
        s_at[tid] = (s_t[tid * 4 + 2] - s_t[tid * 4]) * (s_t[tid * 4 + 3] - s_t[tid * 4 + 1]);
    if (!STORED) __syncthreads();
    const unsigned vm = vmask[b];
    const bool av = vm != 0;

    int p = bx * 256 + tid;
    float a_ll = 0.f, a_lm = 0.f, a_lcp = 0.f, a_np = 0.f, a_np1 = 0.f;
    if (p < P) {
        float4 pr = priors[p];
        float btv; int bti_;
        if constexpr (STORED) {
            btv = btvA[(size_t)b * P + p];
            bti_ = btiA[(size_t)b * P + p];
        } else {
            float hx = pr.z * 0.5f, hy = pr.w * 0.5f;
            float px0 = pr.x - hx, py0 = pr.y - hy;
            float px1 = pr.x + hx, py1 = pr.y + hy;
            float ap = (px1 - px0) * (py1 - py0);
            btv = -1.f; bti_ = 0;
            #pragma unroll
            for (int g = 0; g < GN; ++g) {
                float lx = fmaxf(s_t[g * 4], px0), ly = fmaxf(s_t[g * 4 + 1], py0);
                float rx = fminf(s_t[g * 4 + 2], px1), ry = fminf(s_t[g * 4 + 3], py1);
                float iw = fmaxf(rx - lx, 0.f), ih = fmaxf(ry - ly, 0.f);
                float inter = iw * ih;
                float iou = inter * RCP(s_at[g] + ap - inter);
                if (iou > btv) { btv = iou; bti_ = g; }
            }
        }
        unsigned npk = ~(unsigned)p;
        int fidx = -1; bool fv = false;
        #pragma unroll
        for (int g = 0; g < GN; ++g)
            if (s_kl[g] == npk) { fidx = g; fv = fv || ((vm >> g) & 1u); }
        bool thr = btv >= 0.35f;
        int bti2 = fidx >= 0 ? fidx : bti_;
        bool pos = av && (fv || thr);                  // conf != 0
        float lab = s_lab[bti2];

        float2 c = cls[(size_t)b * P + p];
        float d = c.y - c.x, m0 = fmaxf(d, 0.f);
        float lse = m0 + __logf(__expf(-m0) + __expf(d - m0));   // logz - c.x >= 0
        bc[(size_t)b * P + p] = pos ? 0.f : lse;

        if (pos) {
            a_np = 1.f;
            a_lcp = lse - d;                           // logz - c.y
            float tx0 = s_t[bti2 * 4], ty0 = s_t[bti2 * 4 + 1];
            float tx1 = s_t[bti2 * 4 + 2], ty1 = s_t[bti2 * 4 + 3];
            float rw = RCP(pr.z), rh = RCP(pr.w);
            float e0 = ((tx0 + tx1) * 0.5f - pr.x) * rw * 10.f;
            float e1 = ((ty0 + ty1) * 0.5f - pr.y) * rh * 10.f;
            float e2 = __logf((tx1 - tx0) * rw) * 5.f;
            float e3 = __logf((ty1 - ty0) * rh) * 5.f;
            float4 ld = loc[(size_t)b * P + p];
            a_ll = sl1(ld.x - e0) + sl1(ld.y - e1) + sl1(ld.z - e2) + sl1(ld.w - e3);
            if (lab > 0.f) {                           // conf > 0
                a_np1 = 1.f;
                const float* lp = lmd + ((size_t)b * P + p) * 10;
                #pragma unroll
                for (int q = 0; q < 5; ++q) {
                    float gx = (s_lm[bti2 * 10 + 2 * q]     - pr.x) * rw * 10.f;
                    float gy = (s_lm[bti2 * 10 + 2 * q + 1] - pr.y) * rh * 10.f;
                    a_lm += sl1(lp[2 * q] - gx) + sl1(lp[2 * q + 1] - gy);
                }
            }
        }
    }
    // single-barrier block reduce of the 5 partials
    #pragma unroll
    for (int o = 32; o > 0; o >>= 1) {
        a_ll  += __shfl_down(a_ll,  o, 64);
        a_lm  += __shfl_down(a_lm,  o, 64);
        a_lcp += __shfl_down(a_lcp, o, 64);
        a_np  += __shfl_down(a_np,  o, 64);
        a_np1 += __shfl_down(a_np1, o, 64);
    }
    if (lane == 0) {
        s_red[w][0] = a_ll; s_red[w][1] = a_lm; s_red[w][2] = a_lcp;
        s_red[w][3] = a_np; s_red[w][4] = a_np1;
    }
    __syncthreads();
    if (tid == 0) {
        float* pp = part + ((size_t)b * NB + bx) * 8;
        #pragma unroll
        for (int j = 0; j < 5; ++j)
            pp[j] = s_red[0][j] + s_red[1][j] + s_red[2][j] + s_red[3][j];
    }
}

// ---- k_select: per-batch partial reduce + exact top-k sum via bisection ----
constexpr int SNT = 1024;
constexpr int SNI = 17;     // ceil(16800 / 1024)
__global__ __launch_bounds__(SNT)
void k_select(const float* __restrict__ bc, const float* __restrict__ part,
              float* __restrict__ part2, int P, int NB) {
    const int b = blockIdx.x, tid = threadIdx.x;
    const int lane = tid & 63, w = tid >> 6;
    unsigned ul[SNI];
    #pragma unroll
    for (int i = 0; i < SNI; ++i) {
        int idx = i * SNT + tid;
        ul[i] = idx < P ? __float_as_uint(bc[(size_t)b * P + idx]) : 0u;
    }
    __shared__ float s_r[5];
    if (w < 5) {                                        // wave j reduces sum j
        float s = 0.f;
        for (int bx = lane; bx < NB; bx += 64) s += part[((size_t)b * NB + bx) * 8 + w];
        #pragma unroll
        for (int o = 32; o > 0; o >>= 1) s += __shfl_down(s, o, 64);
        if (lane == 0) s_r[w] = s;
    }
    __syncthreads();
    float t_ll = s_r[0], t_lm = s_r[1], t_lcp = s_r[2], t_np = s_r[3], t_np1 = s_r[4];
    int np = (int)(t_np + 0.5f);
    int k = np * 7;
    if (k > P - 1) k = P - 1;

    __shared__ int s_ri[16];
    __shared__ int s_i0;
    __shared__ float s_rf[16];
    float topk = 0.f;
    if (k > 0) {
        unsigned lo = 0u, hi = 0x7f800000u;             // finite non-negative values
        while (lo < hi) {                               // uniform across block
            unsigned mid = lo + ((hi - lo + 1) >> 1);
            int cnt = 0;
            #pragma unroll
            for (int i = 0; i < SNI; ++i) cnt += (ul[i] >= mid) ? 1 : 0;
            #pragma unroll
            for (int o = 32; o > 0; o >>= 1) cnt += __shfl_down(cnt, o, 64);
            if (lane == 0) s_ri[w] = cnt;
            __syncthreads();
            if (tid == 0) {
                int r = 0;
                #pragma unroll
                for (int q = 0; q < 16; ++q) r += s_ri[q];
                s_i0 = r;
            }
            __syncthreads();
            if (s_i0 >= k) lo = mid; else hi = mid - 1;
        }
        float fT = __uint_as_float(lo);                 // k-th largest (bit-exact)
        float s = 0.f; int c = 0;
        #pragma unroll
        for (int i = 0; i < SNI; ++i)
            if (ul[i] > lo) { s += __uint_as_float(ul[i]); c++; }
        #pragma unroll
        for (int o = 32; o > 0; o >>= 1) {
            s += __shfl_down(s, o, 64);
            c += __shfl_down(c, o, 64);
        }
        if (lane == 0) { s_rf[w] = s; s_ri[w] = c; }
        __syncthreads();
        if (tid == 0) {
            float ts = 0.f; int tc = 0;
            #pragma unroll
            for (int q = 0; q < 16; ++q) { ts += s_rf[q]; tc += s_ri[q]; }
            topk = ts + (float)(k - tc) * fT;           // ties contribute (k-cnt)*T
        }
    }
    if (tid == 0) {
        float* pp = part2 + b * 8;
        pp[0] = t_ll; pp[1] = t_lm; pp[2] = t_lcp;
        pp[3] = topk; pp[4] = t_np; pp[5] = t_np1;
    }
}

__global__ void k_final(const float* __restrict__ part2, float* __restrict__ out, int B) {
    int lane = threadIdx.x;
    float ll = 0, lm = 0, lcp = 0, tk = 0, np = 0, np1 = 0;
    for (int b = lane; b < B; b += 64) {
        const float* pp = part2 + b * 8;
        ll += pp[0]; lm += pp[1]; lcp += pp[2];
        tk += pp[3]; np += pp[4]; np1 += pp[5];
    }
    #pragma unroll
    for (int o = 32; o > 0; o >>= 1) {
        ll  += __shfl_down(ll, o, 64);
        lm  += __shfl_down(lm, o, 64);
        lcp += __shfl_down(lcp, o, 64);
        tk  += __shfl_down(tk, o, 64);
        np  += __shfl_down(np, o, 64);
        np1 += __shfl_down(np1, o, 64);
    }
    if (lane == 0) {
        float N = fmaxf(np, 1.f), N1 = fmaxf(np1, 1.f);
        out[0] = ll / N;
        out[1] = (lcp + tk) / N;
        out[2] = lm / N1;
    }
}

extern "C" void kernel_launch(void* const* d_in, const int* in_sizes, int n_in,
                              void* d_out, int out_size, void* d_ws, size_t ws_size,
                              hipStream_t stream) {
    const float2* cls    = (const float2*)d_in[0];
    const float4* loc    = (const float4*)d_in[1];
    const float* lmd     = (const float*)d_in[2];
    const float4* priors = (const float4*)d_in[3];
    const float* targets = (const float*)d_in[4];
    int P = in_sizes[3] / 4;          // 16800
    int B = (in_sizes[1] / 4) / P;    // 64
    int NB = (P + 255) / 256;         // 66

    // ws layout (bytes)
    size_t off = 0;
    unsigned long long* wkeys = (unsigned long long*)d_ws;  off += (size_t)B * NB * GN * 8;
    unsigned long long* keys  = (unsigned long long*)((char*)d_ws + off); off += (size_t)B * GN * 8;
    unsigned* vmask = (unsigned*)((char*)d_ws + off); off += (size_t)B * 4;
    off = (off + 255) & ~(size_t)255;
    float* part  = (float*)((char*)d_ws + off); off += (size_t)B * NB * 8 * 4;
    float* part2 = (float*)((char*)d_ws + off); off += (size_t)B * 8 * 4;
    off = (off + 255) & ~(size_t)255;
    float* bc = (float*)((char*)d_ws + off); off += (size_t)B * P * 4;
    float* btv = (float*)((char*)d_ws + off); off += (size_t)B * P * 4;
    unsigned char* bti = (unsigned char*)((char*)d_ws + off); off += (size_t)B * P;
    bool stored = ws_size >= off;

    dim3 grid(NB, B);
    if (stored) {
        k_prior<true><<<grid, 256, 0, stream>>>(priors, targets, wkeys, btv, bti, P, NB);
        k_keys<<<B, 256, 0, stream>>>(wkeys, keys, vmask, NB);
        k_match<true><<<grid, 256, 0, stream>>>(cls, loc, lmd, priors, targets, keys, vmask,
                                                btv, bti, bc, part, P, NB);
    } else {
        k_prior<false><<<grid, 256, 0, stream>>>(priors, targets, wkeys, btv, bti, P, NB);
        k_keys<<<B, 256, 0, stream>>>(wkeys, keys, vmask, NB);
        k_match<false><<<grid, 256, 0, stream>>>(cls, loc, lmd, priors, targets, keys, vmask,
                                                 btv, bti, bc, part, P, NB);
    }
    k_select<<<B, SNT, 0, stream>>>(bc, part, part2, P, NB);
    k_final<<<1, 64, 0, stream>>>(part2, (float*)d_out, B);
}

// Round 5
// 89.914 us; speedup vs baseline: 7.5707x; 1.5359x over previous
//
#include <hip/hip_runtime.h>
#include <hip/hip_bf16.h>
#include <math.h>

// MultiBoxLoss: B=64, P=16800, G=32, C=2. Atomic-free, 4-kernel pipeline:
// k_gt     (B x G/4 blocks, 512 thr): transposed per-gt best-prior argmax.
//          One block scans ALL priors for 4 gts -> final keys directly.
// k_match  (NB x B blocks, 256 thr):  IoU inline (cheap), forced-match via
//          key index compare, conf + losses, per-block partial sums.
// k_select (B blocks, 1024 thr):      reduce partials; exact k-th largest by
//          bisection on float bits over register-resident conf-losses.
// k_final  (1 wave): 64 rows -> 3 scalars.

#define RCP(x) __builtin_amdgcn_rcpf(x)

constexpr int GN = 32;

__device__ __forceinline__ float sl1(float x) {
    float a = fabsf(x);
    return a < 1.f ? 0.5f * a * a : a - 0.5f;
}

// ---- k_gt: per-gt best prior (max iou, ties -> smallest p) ----
constexpr int GPB = 4;     // gts per block
constexpr int GNT = 512;   // threads (8 waves)
__global__ __launch_bounds__(GNT)
void k_gt(const float4* __restrict__ priors, const float* __restrict__ targets,
          unsigned long long* __restrict__ keys, int P, int G) {
    const int b = blockIdx.y, g0 = blockIdx.x * GPB, tid = threadIdx.x;
    const int lane = tid & 63, w = tid >> 6;
    __shared__ float4 s_box[GPB];
    __shared__ float  s_at[GPB];
    __shared__ unsigned long long s_wk[GNT / 64][GPB];
    if (tid < GPB) {
        const float* t = targets + ((size_t)b * G + g0 + tid) * 15;
        float4 v = make_float4(t[0], t[1], t[2], t[3]);
        s_box[tid] = v;
        s_at[tid] = (v.z - v.x) * (v.w - v.y);
    }
    __syncthreads();
    float4 tb0 = s_box[0], tb1 = s_box[1], tb2 = s_box[2], tb3 = s_box[3];
    float at0 = s_at[0], at1 = s_at[1], at2 = s_at[2], at3 = s_at[3];

    float bv[GPB]; int bp[GPB];
    #pragma unroll
    for (int j = 0; j < GPB; ++j) { bv[j] = -1.f; bp[j] = 0; }

    for (int p = tid; p < P; p += GNT) {     // ascending p: '>' keeps smallest p
        float4 pr = priors[p];
        float hx = pr.z * 0.5f, hy = pr.w * 0.5f;
        float px0 = pr.x - hx, py0 = pr.y - hy;
        float px1 = pr.x + hx, py1 = pr.y + hy;
        float ap = (px1 - px0) * (py1 - py0);
        #pragma unroll
        for (int j = 0; j < GPB; ++j) {
            float4 tb = j == 0 ? tb0 : (j == 1 ? tb1 : (j == 2 ? tb2 : tb3));
            float at = j == 0 ? at0 : (j == 1 ? at1 : (j == 2 ? at2 : at3));
            float lx = fmaxf(tb.x, px0), ly = fmaxf(tb.y, py0);
            float rx = fminf(tb.z, px1), ry = fminf(tb.w, py1);
            float iw = fmaxf(rx - lx, 0.f), ih = fmaxf(ry - ly, 0.f);
            float inter = iw * ih;
            float iou = inter * RCP(at + ap - inter);
            if (iou > bv[j]) { bv[j] = iou; bp[j] = p; }
        }
    }
    #pragma unroll
    for (int j = 0; j < GPB; ++j) {
        unsigned long long key =
            ((unsigned long long)__float_as_uint(bv[j]) << 32) | ~(unsigned)bp[j];
        #pragma unroll
        for (int o = 32; o > 0; o >>= 1) {
            unsigned long long t = __shfl_down(key, o, 64);
            if (t > key) key = t;
        }
        if (lane == 0) s_wk[w][j] = key;
    }
    __syncthreads();
    if (tid < GPB) {
        unsigned long long m = 0ull;
        #pragma unroll
        for (int q = 0; q < GNT / 64; ++q) { unsigned long long t = s_wk[q][tid]; if (t > m) m = t; }
        keys[b * G + g0 + tid] = m;
    }
}

// ---- k_match: IoU + forced-match + conf + losses; per-block partials ----
__global__ __launch_bounds__(256)
void k_match(const float2* __restrict__ cls, const float4* __restrict__ loc,
             const float* __restrict__ lmd, const float4* __restrict__ priors,
             const float* __restrict__ targets,
             const unsigned long long* __restrict__ keys,
             float* __restrict__ bc, float* __restrict__ part, int P, int NB) {
    const int b = blockIdx.y, bx = blockIdx.x, tid = threadIdx.x;
    const int lane = tid & 63, w = tid >> 6;
    __shared__ float s_t[GN * 4];
    __shared__ float s_at[GN];
    __shared__ float s_lm[GN * 10];
    __shared__ float s_lab[GN];
    __shared__ unsigned s_kl[GN];
    __shared__ unsigned s_vm;
    __shared__ float s_red[4][8];
    for (int i = tid; i < GN * 15; i += 256) {
        int g = i / 15, j = i - g * 15;
        float v = targets[((size_t)b * GN + g) * 15 + j];
        if (j < 4) s_t[g * 4 + j] = v;
        else if (j < 14) s_lm[g * 10 + (j - 4)] = v;
        else s_lab[g] = v;
    }
    bool gvalid = false;
    if (tid < GN) {
        unsigned long long key = keys[b * GN + tid];
        s_kl[tid] = (unsigned)key;
        gvalid = __uint_as_float((unsigned)(key >> 32)) >= 0.2f;
    }
    if (w == 0) {
        unsigned long long bal = __ballot(gvalid);   // lanes 0..31 = gts 0..31
        if (tid == 0) s_vm = (unsigned)bal;
    }
    __syncthreads();
    if (tid < GN)
        s_at[tid] = (s_t[tid * 4 + 2] - s_t[tid * 4]) * (s_t[tid * 4 + 3] - s_t[tid * 4 + 1]);
    __syncthreads();
    const unsigned vm = s_vm;
    const bool av = vm != 0;

    int p = bx * 256 + tid;
    float a_ll = 0.f, a_lm = 0.f, a_lcp = 0.f, a_np = 0.f, a_np1 = 0.f;
    if (p < P) {
        float4 pr = priors[p];
        float hx = pr.z * 0.5f, hy = pr.w * 0.5f;
        float px0 = pr.x - hx, py0 = pr.y - hy;
        float px1 = pr.x + hx, py1 = pr.y + hy;
        float ap = (px1 - px0) * (py1 - py0);
        float btv = -1.f; int bti_ = 0;
        #pragma unroll
        for (int g = 0; g < GN; ++g) {
            float lx = fmaxf(s_t[g * 4], px0), ly = fmaxf(s_t[g * 4 + 1], py0);
            float rx = fminf(s_t[g * 4 + 2], px1), ry = fminf(s_t[g * 4 + 3], py1);
            float iw = fmaxf(rx - lx, 0.f), ih = fmaxf(ry - ly, 0.f);
            float inter = iw * ih;
            float iou = inter * RCP(s_at[g] + ap - inter);
            if (iou > btv) { btv = iou; bti_ = g; }      // first-g argmax
        }
        unsigned npk = ~(unsigned)p;
        int fidx = -1; bool fv = false;
        #pragma unroll
        for (int g = 0; g < GN; ++g)
            if (s_kl[g] == npk) { fidx = g; fv = fv || ((vm >> g) & 1u); }  // largest g wins
        int bti2 = fidx >= 0 ? fidx : bti_;
        bool pos = av && (fv || btv >= 0.35f);           // conf != 0
        float lab = s_lab[bti2];

        float2 c = cls[(size_t)b * P + p];
        float d = c.y - c.x, m0 = fmaxf(d, 0.f);
        float lse = m0 + __logf(__expf(-m0) + __expf(d - m0));   // logz - c.x >= 0
        bc[(size_t)b * P + p] = pos ? 0.f : lse;

        if (pos) {
            a_np = 1.f;
            a_lcp = lse - d;                             // logz - c.y
            float tx0 = s_t[bti2 * 4], ty0 = s_t[bti2 * 4 + 1];
            float tx1 = s_t[bti2 * 4 + 2], ty1 = s_t[bti2 * 4 + 3];
            float rw = RCP(pr.z), rh = RCP(pr.w);
            float e0 = ((tx0 + tx1) * 0.5f - pr.x) * rw * 10.f;
            float e1 = ((ty0 + ty1) * 0.5f - pr.y) * rh * 10.f;
            float e2 = __logf((tx1 - tx0) * rw) * 5.f;
            float e3 = __logf((ty1 - ty0) * rh) * 5.f;
            float4 ld = loc[(size_t)b * P + p];
            a_ll = sl1(ld.x - e0) + sl1(ld.y - e1) + sl1(ld.z - e2) + sl1(ld.w - e3);
            if (lab > 0.f) {                             // conf > 0
                a_np1 = 1.f;
                const float* lp = lmd + ((size_t)b * P + p) * 10;
                #pragma unroll
                for (int q = 0; q < 5; ++q) {
                    float gx = (s_lm[bti2 * 10 + 2 * q]     - pr.x) * rw * 10.f;
                    float gy = (s_lm[bti2 * 10 + 2 * q + 1] - pr.y) * rh * 10.f;
                    a_lm += sl1(lp[2 * q] - gx) + sl1(lp[2 * q + 1] - gy);
                }
            }
        }
    }
    #pragma unroll
    for (int o = 32; o > 0; o >>= 1) {
        a_ll  += __shfl_down(a_ll,  o, 64);
        a_lm  += __shfl_down(a_lm,  o, 64);
        a_lcp += __shfl_down(a_lcp, o, 64);
        a_np  += __shfl_down(a_np,  o, 64);
        a_np1 += __shfl_down(a_np1, o, 64);
    }
    if (lane == 0) {
        s_red[w][0] = a_ll; s_red[w][1] = a_lm; s_red[w][2] = a_lcp;
        s_red[w][3] = a_np; s_red[w][4] = a_np1;
    }
    __syncthreads();
    if (tid == 0) {
        float* pp = part + ((size_t)b * NB + bx) * 8;
        #pragma unroll
        for (int j = 0; j < 5; ++j)
            pp[j] = s_red[0][j] + s_red[1][j] + s_red[2][j] + s_red[3][j];
    }
}

// ---- k_select: per-batch reduce + exact top-k sum via bit bisection ----
constexpr int SNT = 1024;
constexpr int SNI = 17;     // ceil(16800 / 1024)
__global__ __launch_bounds__(SNT)
void k_select(const float* __restrict__ bc, const float* __restrict__ part,
              float* __restrict__ part2, int P, int NB) {
    const int b = blockIdx.x, tid = threadIdx.x;
    const int lane = tid & 63, w = tid >> 6;
    unsigned ul[SNI];
    #pragma unroll
    for (int i = 0; i < SNI; ++i) {
        int idx = i * SNT + tid;
        ul[i] = idx < P ? __float_as_uint(bc[(size_t)b * P + idx]) : 0u;
    }
    __shared__ float s_r[5];
    if (w < 5) {                                        // wave j reduces sum j
        float s = 0.f;
        for (int bx = lane; bx < NB; bx += 64) s += part[((size_t)b * NB + bx) * 8 + w];
        #pragma unroll
        for (int o = 32; o > 0; o >>= 1) s += __shfl_down(s, o, 64);
        if (lane == 0) s_r[w] = s;
    }
    __syncthreads();
    float t_ll = s_r[0], t_lm = s_r[1], t_lcp = s_r[2], t_np = s_r[3], t_np1 = s_r[4];
    int np = (int)(t_np + 0.5f);
    int k = np * 7;
    if (k > P - 1) k = P - 1;

    __shared__ int s_ri[16];
    __shared__ int s_i0;
    __shared__ float s_rf[16];
    float topk = 0.f;
    if (k > 0) {
        unsigned lo = 0u, hi = 0x7f800000u;
        while (lo < hi) {                               // uniform across block
            unsigned mid = lo + ((hi - lo + 1) >> 1);
            int cnt = 0;
            #pragma unroll
            for (int i = 0; i < SNI; ++i) cnt += (ul[i] >= mid) ? 1 : 0;
            #pragma unroll
            for (int o = 32; o > 0; o >>= 1) cnt += __shfl_down(cnt, o, 64);
            if (lane == 0) s_ri[w] = cnt;
            __syncthreads();
            if (tid == 0) {
                int r = 0;
                #pragma unroll
                for (int q = 0; q < 16; ++q) r += s_ri[q];
                s_i0 = r;
            }
            __syncthreads();
            if (s_i0 >= k) lo = mid; else hi = mid - 1;
        }
        float fT = __uint_as_float(lo);                 // k-th largest (bit-exact)
        float s = 0.f; int c = 0;
        #pragma unroll
        for (int i = 0; i < SNI; ++i)
            if (ul[i] > lo) { s += __uint_as_float(ul[i]); c++; }
        #pragma unroll
        for (int o = 32; o > 0; o >>= 1) {
            s += __shfl_down(s, o, 64);
            c += __shfl_down(c, o, 64);
        }
        if (lane == 0) { s_rf[w] = s; s_ri[w] = c; }
        __syncthreads();
        if (tid == 0) {
            float ts = 0.f; int tc = 0;
            #pragma unroll
            for (int q = 0; q < 16; ++q) { ts += s_rf[q]; tc += s_ri[q]; }
            topk = ts + (float)(k - tc) * fT;           // ties add (k-cnt)*T
        }
    }
    if (tid == 0) {
        float* pp = part2 + b * 8;
        pp[0] = t_ll; pp[1] = t_lm; pp[2] = t_lcp;
        pp[3] = topk; pp[4] = t_np; pp[5] = t_np1;
    }
}

__global__ void k_final(const float* __restrict__ part2, float* __restrict__ out, int B) {
    int lane = threadIdx.x;
    float ll = 0, lm = 0, lcp = 0, tk = 0, np = 0, np1 = 0;
    for (int b = lane; b < B; b += 64) {
        const float* pp = part2 + b * 8;
        ll += pp[0]; lm += pp[1]; lcp += pp[2];
        tk += pp[3]; np += pp[4]; np1 += pp[5];
    }
    #pragma unroll
    for (int o = 32; o > 0; o >>= 1) {
        ll  += __shfl_down(ll, o, 64);
        lm  += __shfl_down(lm, o, 64);
        lcp += __shfl_down(lcp, o, 64);
        tk  += __shfl_down(tk, o, 64);
        np  += __shfl_down(np, o, 64);
        np1 += __shfl_down(np1, o, 64);
    }
    if (lane == 0) {
        float N = fmaxf(np, 1.f), N1 = fmaxf(np1, 1.f);
        out[0] = ll / N;
        out[1] = (lcp + tk) / N;
        out[2] = lm / N1;
    }
}

extern "C" void kernel_launch(void* const* d_in, const int* in_sizes, int n_in,
                              void* d_out, int out_size, void* d_ws, size_t ws_size,
                              hipStream_t stream) {
    const float2* cls    = (const float2*)d_in[0];
    const float4* loc    = (const float4*)d_in[1];
    const float* lmd     = (const float*)d_in[2];
    const float4* priors = (const float4*)d_in[3];
    const float* targets = (const float*)d_in[4];
    int P = in_sizes[3] / 4;          // 16800
    int B = (in_sizes[1] / 4) / P;    // 64
    int NB = (P + 255) / 256;         // 66
    int G = in_sizes[4] / (15 * B);   // 32

    size_t off = 0;
    unsigned long long* keys = (unsigned long long*)d_ws; off += (size_t)B * G * 8;
    float* part  = (float*)((char*)d_ws + off); off += (size_t)B * NB * 8 * 4;
    float* part2 = (float*)((char*)d_ws + off); off += (size_t)B * 8 * 4;
    off = (off + 255) & ~(size_t)255;
    float* bc = (float*)((char*)d_ws + off);

    dim3 ggt((G + GPB - 1) / GPB, B);
    k_gt<<<ggt, GNT, 0, stream>>>(priors, targets, keys, P, G);
    dim3 gm(NB, B);
    k_match<<<gm, 256, 0, stream>>>(cls, loc, lmd, priors, targets, keys, bc, part, P, NB);
    k_select<<<B, SNT, 0, stream>>>(bc, part, part2, P, NB);
    k_final<<<1, 64, 0, stream>>>(part2, (float*)d_out, B);
}